// Round 2
// baseline (61.307 us; speedup 1.0000x reference)
//
#include <hip/hip_runtime.h>
#include <hip/hip_bf16.h>

// Segment mean: N values, sorted segment ids, NC segments.
// Pass 1: wave-level segmented scan -> one atomicAdd per run per wave.
// Pass 2: divide by count.

__global__ void seg_sum_kernel(const float* __restrict__ x,
                               const void* __restrict__ seg,
                               float* __restrict__ sums,
                               float* __restrict__ cnts,
                               int n) {
    const int* seg32 = (const int*)seg;
    const long long* seg64 = (const long long*)seg;
    // dtype detection: for int64 storage, int32 word [n-1] is a high word (0).
    // For int32 storage it is the last (largest) sorted id, nonzero.
    const bool is64 = (seg32[n - 1] == 0);

    const int i = blockIdx.x * blockDim.x + threadIdx.x;
    const int lane = threadIdx.x & 63;

    int id = -1;
    float val = 0.0f;
    const bool active = (i < n);
    if (active) {
        id = is64 ? (int)seg64[i] : seg32[i];
        val = x[i];
    }

    // Segmented inclusive scan over the 64-lane wave (runs of equal id).
    // Non-propagating guard is exact because ids are sorted: equality at
    // distance `off` implies the whole span is one run.
    #pragma unroll
    for (int off = 1; off < 64; off <<= 1) {
        float ov = __shfl_up(val, off);
        int oid = __shfl_up(id, off);
        if (lane >= off && oid == id) val += ov;
    }

    // Head flags (start of run), ballot over 64 lanes.
    int prev_id = __shfl_up(id, 1);
    bool head = active && ((lane == 0) || (prev_id != id));
    unsigned long long heads = __ballot(head);

    // Tail lanes do the atomics.
    int next_id = __shfl_down(id, 1);
    bool tail = active && ((lane == 63) || (i == n - 1) || (next_id != id));
    if (tail) {
        unsigned long long mask = heads & (~0ULL >> (63 - lane));
        int start = 63 - __clzll(mask);   // most recent head at/below this lane
        float runlen = (float)(lane - start + 1);
        atomicAdd(&sums[id], val);
        atomicAdd(&cnts[id], runlen);
    }
}

__global__ void finalize_kernel(float* __restrict__ out,
                                const float* __restrict__ cnts,
                                int nc) {
    int c = blockIdx.x * blockDim.x + threadIdx.x;
    if (c < nc) {
        out[c] = out[c] / fmaxf(cnts[c], 1.0f);
    }
}

extern "C" void kernel_launch(void* const* d_in, const int* in_sizes, int n_in,
                              void* d_out, int out_size, void* d_ws, size_t ws_size,
                              hipStream_t stream) {
    const float* x = (const float*)d_in[0];
    const void* seg = d_in[1];
    const int n = in_sizes[0];     // 16777216
    const int nc = out_size;       // 262144

    float* sums = (float*)d_out;
    float* cnts = (float*)d_ws;

    // Must zero every call: harness does not re-poison between graph replays.
    hipMemsetAsync(sums, 0, (size_t)nc * sizeof(float), stream);
    hipMemsetAsync(cnts, 0, (size_t)nc * sizeof(float), stream);

    const int block = 256;
    const int grid = (n + block - 1) / block;
    seg_sum_kernel<<<grid, block, 0, stream>>>(x, seg, sums, cnts, n);

    const int fgrid = (nc + block - 1) / block;
    finalize_kernel<<<fgrid, block, 0, stream>>>(sums, cnts, nc);
}

// Round 3
// 41.537 us; speedup vs baseline: 1.4760x; 1.4760x over previous
//
#include <hip/hip_runtime.h>
#include <hip/hip_bf16.h>

// Segment mean: N values, sorted segment ids, NC segments.
// VPT elements per thread: sequential run-merge in registers, wave-level
// segmented scan on per-thread trailing runs (equality guard is exact
// because ids are sorted), one atomic pair per run/chain-end.

#define VPT 8

__global__ void seg_sum_kernel(const float* __restrict__ x,
                               const void* __restrict__ seg,
                               float* __restrict__ sums,
                               float* __restrict__ cnts,
                               int n) {
    const int* s32 = (const int*)seg;
    const long long* s64 = (const long long*)seg;
    // dtype sniff: for int64 storage, int32 word [n-1] is a high word (0,
    // ids < 2^18). For int32 storage it is the largest sorted id (nonzero).
    const bool is64 = (s32[n - 1] == 0);

    const long long base = (long long)(blockIdx.x * (long long)blockDim.x + threadIdx.x) * VPT;
    const int lane = threadIdx.x & 63;

    int ids[VPT];
    float vals[VPT];
    int nv = 0;
    if (base < n) {
        long long rem = (long long)n - base;
        nv = (rem >= VPT) ? VPT : (int)rem;
    }

    if (nv == VPT) {
        const float4* xv = (const float4*)(x + base);
        float4 a = xv[0], b = xv[1];
        vals[0] = a.x; vals[1] = a.y; vals[2] = a.z; vals[3] = a.w;
        vals[4] = b.x; vals[5] = b.y; vals[6] = b.z; vals[7] = b.w;
        if (is64) {
            const longlong2* iv = (const longlong2*)(s64 + base);
            #pragma unroll
            for (int k = 0; k < 4; ++k) {
                longlong2 t = iv[k];
                ids[2 * k]     = (int)t.x;
                ids[2 * k + 1] = (int)t.y;
            }
        } else {
            const int4* iv = (const int4*)(s32 + base);
            int4 t0 = iv[0], t1 = iv[1];
            ids[0] = t0.x; ids[1] = t0.y; ids[2] = t0.z; ids[3] = t0.w;
            ids[4] = t1.x; ids[5] = t1.y; ids[6] = t1.z; ids[7] = t1.w;
        }
    } else {
        #pragma unroll
        for (int k = 0; k < VPT; ++k) {
            if (k < nv) {
                ids[k]  = is64 ? (int)s64[base + k] : s32[base + k];
                vals[k] = x[base + k];
            } else {
                ids[k]  = -1;
                vals[k] = 0.0f;
            }
        }
    }

    // Sequential run-merge within the thread; flush closed runs immediately.
    int   cur = (nv > 0) ? ids[0] : -1;
    float s   = (nv > 0) ? vals[0] : 0.0f;
    float c   = (nv > 0) ? 1.0f : 0.0f;
    #pragma unroll
    for (int k = 1; k < VPT; ++k) {
        if (k < nv) {
            if (ids[k] == cur) {
                s += vals[k];
                c += 1.0f;
            } else {
                atomicAdd(&sums[cur], s);
                atomicAdd(&cnts[cur], c);
                cur = ids[k];
                s = vals[k];
                c = 1.0f;
            }
        }
    }

    // Wave segmented scan over trailing runs. Sortedness makes the
    // equality guard exact: lid[i-off]==lid[i] implies all elements in
    // between (and thus all intermediate threads) share that id.
    int lid = cur;
    #pragma unroll
    for (int off = 1; off < 64; off <<= 1) {
        float os = __shfl_up(s, off);
        float oc = __shfl_up(c, off);
        int  oid = __shfl_up(lid, off);
        if (lane >= off && oid == lid) {
            s += os;
            c += oc;
        }
    }

    // Chain-end lanes emit. Next lane absorbs this chain iff its trailing
    // id matches (which, by sortedness, implies it is transparent).
    int nid = __shfl_down(lid, 1);
    bool emit = (lid >= 0) && ((lane == 63) || (nid != lid));
    if (emit) {
        atomicAdd(&sums[lid], s);
        atomicAdd(&cnts[lid], c);
    }
}

__global__ void finalize_kernel(float* __restrict__ out,
                                const float* __restrict__ cnts,
                                int nc) {
    int cidx = blockIdx.x * blockDim.x + threadIdx.x;
    if (cidx < nc) {
        out[cidx] = out[cidx] / fmaxf(cnts[cidx], 1.0f);
    }
}

extern "C" void kernel_launch(void* const* d_in, const int* in_sizes, int n_in,
                              void* d_out, int out_size, void* d_ws, size_t ws_size,
                              hipStream_t stream) {
    const float* x = (const float*)d_in[0];
    const void* seg = d_in[1];
    const int n = in_sizes[0];     // 16777216
    const int nc = out_size;       // 262144

    float* sums = (float*)d_out;
    float* cnts = (float*)d_ws;

    // Must zero every call: harness does not re-poison between graph replays.
    hipMemsetAsync(sums, 0, (size_t)nc * sizeof(float), stream);
    hipMemsetAsync(cnts, 0, (size_t)nc * sizeof(float), stream);

    const int block = 256;
    const long long elems_per_block = (long long)block * VPT;
    const int grid = (int)((n + elems_per_block - 1) / elems_per_block);
    seg_sum_kernel<<<grid, block, 0, stream>>>(x, seg, sums, cnts, n);

    const int fgrid = (nc + block - 1) / block;
    finalize_kernel<<<fgrid, block, 0, stream>>>(sums, cnts, nc);
}

// Round 5
// 41.200 us; speedup vs baseline: 1.4881x; 1.0082x over previous
//
#include <hip/hip_runtime.h>
#include <hip/hip_bf16.h>

// Segment mean: N values, sorted segment ids, NC segments.
// VPT=16 elements/thread: 12 vector loads in flight, sequential run-merge
// in registers, wave segmented scan on trailing runs, atomics into d_ws,
// streaming finalize into d_out.

#define VPT 16

__global__ void seg_sum_kernel(const float* __restrict__ x,
                               const void* __restrict__ seg,
                               float* __restrict__ sums,
                               float* __restrict__ cnts,
                               int n) {
    const int* s32 = (const int*)seg;
    const long long* s64 = (const long long*)seg;
    // dtype sniff: for int64 storage, int32 word [n-1] is a high word (0,
    // ids < 2^18). For int32 storage it is the largest sorted id (nonzero).
    const bool is64 = (s32[n - 1] == 0);

    const long long base = (long long)(blockIdx.x * (long long)blockDim.x + threadIdx.x) * VPT;
    const int lane = threadIdx.x & 63;

    int ids[VPT];
    float vals[VPT];
    int nv = 0;
    if (base < n) {
        long long rem = (long long)n - base;
        nv = (rem >= VPT) ? VPT : (int)rem;
    }

    if (nv == VPT) {
        const float4* xv = (const float4*)(x + base);
        #pragma unroll
        for (int k = 0; k < 4; ++k) {
            float4 a = xv[k];
            vals[4 * k]     = a.x;
            vals[4 * k + 1] = a.y;
            vals[4 * k + 2] = a.z;
            vals[4 * k + 3] = a.w;
        }
        if (is64) {
            // 16B load covers two int64; low dwords at .x and .z (LE).
            const int4* iv = (const int4*)(s64 + base);
            #pragma unroll
            for (int k = 0; k < 8; ++k) {
                int4 t = iv[k];
                ids[2 * k]     = t.x;
                ids[2 * k + 1] = t.z;
            }
        } else {
            const int4* iv = (const int4*)(s32 + base);
            #pragma unroll
            for (int k = 0; k < 4; ++k) {
                int4 t = iv[k];
                ids[4 * k]     = t.x;
                ids[4 * k + 1] = t.y;
                ids[4 * k + 2] = t.z;
                ids[4 * k + 3] = t.w;
            }
        }
    } else {
        #pragma unroll
        for (int k = 0; k < VPT; ++k) {
            if (k < nv) {
                ids[k]  = is64 ? (int)s64[base + k] : s32[base + k];
                vals[k] = x[base + k];
            } else {
                ids[k]  = -1;
                vals[k] = 0.0f;
            }
        }
    }

    // Sequential run-merge within the thread; flush closed runs immediately.
    int   cur = (nv > 0) ? ids[0] : -1;
    float s   = (nv > 0) ? vals[0] : 0.0f;
    float c   = (nv > 0) ? 1.0f : 0.0f;
    #pragma unroll
    for (int k = 1; k < VPT; ++k) {
        if (k < nv) {
            if (ids[k] == cur) {
                s += vals[k];
                c += 1.0f;
            } else {
                atomicAdd(&sums[cur], s);
                atomicAdd(&cnts[cur], c);
                cur = ids[k];
                s = vals[k];
                c = 1.0f;
            }
        }
    }

    // Wave segmented scan over trailing runs. Sortedness makes the equality
    // guard exact: lid[i-off]==lid[i] implies all threads between share it.
    int lid = cur;
    #pragma unroll
    for (int off = 1; off < 64; off <<= 1) {
        float os = __shfl_up(s, off);
        float oc = __shfl_up(c, off);
        int  oid = __shfl_up(lid, off);
        if (lane >= off && oid == lid) {
            s += os;
            c += oc;
        }
    }

    // Chain-end lanes emit.
    int nid = __shfl_down(lid, 1);
    bool emit = (lid >= 0) && ((lane == 63) || (nid != lid));
    if (emit) {
        atomicAdd(&sums[lid], s);
        atomicAdd(&cnts[lid], c);
    }
}

__global__ void finalize_kernel(float* __restrict__ out,
                                const float* __restrict__ sums,
                                const float* __restrict__ cnts,
                                int nc) {
    int cidx = blockIdx.x * blockDim.x + threadIdx.x;
    if (cidx < nc) {
        out[cidx] = sums[cidx] / fmaxf(cnts[cidx], 1.0f);
    }
}

extern "C" void kernel_launch(void* const* d_in, const int* in_sizes, int n_in,
                              void* d_out, int out_size, void* d_ws, size_t ws_size,
                              hipStream_t stream) {
    const float* x = (const float*)d_in[0];
    const void* seg = d_in[1];
    const int n = in_sizes[0];     // 16777216
    const int nc = out_size;       // 262144

    float* sums = (float*)d_ws;          // [nc]
    float* cnts = (float*)d_ws + nc;     // [nc]
    float* out  = (float*)d_out;

    // One contiguous memset for both accumulators; must re-zero every call
    // (harness does not re-poison between graph replays).
    hipMemsetAsync(sums, 0, (size_t)2 * nc * sizeof(float), stream);

    const int block = 256;
    const long long elems_per_block = (long long)block * VPT;
    const int grid = (int)((n + elems_per_block - 1) / elems_per_block);
    seg_sum_kernel<<<grid, block, 0, stream>>>(x, seg, sums, cnts, n);

    const int fgrid = (nc + block - 1) / block;
    finalize_kernel<<<fgrid, block, 0, stream>>>(out, sums, cnts, nc);
}